// Round 6
// baseline (2896.238 us; speedup 1.0000x reference)
//
#include <hip/hip_runtime.h>
#include <math.h>

#define BATCH 1024
#define TSEQ  2048
#define DIN   5
#define XSTR  6      // xs stride in halves (pad 5->6 for half2 alignment)
#define H     64
#define NOUT  128

typedef _Float16 f16x8  __attribute__((ext_vector_type(8)));
typedef _Float16 half2v __attribute__((ext_vector_type(2)));
typedef float    f32x4  __attribute__((ext_vector_type(4)));

#if __has_builtin(__builtin_amdgcn_fdot2)
__device__ __forceinline__ float FDOT2(half2v a, half2v b, float c) {
    return __builtin_amdgcn_fdot2(a, b, c, false);
}
#else
__device__ __forceinline__ float FDOT2(half2v a, half2v b, float c) {
    return fmaf((float)a.x, (float)b.x, fmaf((float)a.y, (float)b.y, c));
}
#endif

#if __has_builtin(__builtin_amdgcn_rcpf)
__device__ __forceinline__ float rcp_fast(float x) { return __builtin_amdgcn_rcpf(x); }
#else
__device__ __forceinline__ float rcp_fast(float x) { return 1.0f / x; }
#endif

__device__ __forceinline__ float sigmoid_fast(float x) {
    return rcp_fast(1.0f + __expf(-x));
}
__device__ __forceinline__ float tanh_fast(float x) {
    return 1.0f - 2.0f * rcp_fast(__expf(2.0f * x) + 1.0f);
}

// BT=1: one batch elem per block, grid 1024 -> 4 blocks/CU (3-4 resident by regs).
// Transposed MFMA: A = state [y1(64);h2(64)] broadcast to all 16 rows,
// B = weight columns (n = gate-row for this wave's 16 h-units). After the
// 24 MFMAs every lane's D reg0 holds the gate raw for (gate g, hu) -> quad 0
// does the layer-1 update (plus K=5 x-projection via fdot2), quad 2 does the
// layer-2 update, all in registers. 1 KB double-buffered state, ONE barrier/step.
// waves_per_eu(3,4): cap combined VGPR+AGPR ~170 so >=3 waves/SIMD co-reside;
// independent blocks on the same SIMD hide each other's barrier/chain latency.
__global__ __launch_bounds__(256) __attribute__((amdgpu_waves_per_eu(3, 4)))
void lstm_mfma(const float* __restrict__ x,
               const float* __restrict__ Wih0, const float* __restrict__ Whh0,
               const float* __restrict__ bih0, const float* __restrict__ bhh0,
               const float* __restrict__ Wih1, const float* __restrict__ Whh1,
               const float* __restrict__ bih1, const float* __restrict__ bhh1,
               const float* __restrict__ Wfc,  const float* __restrict__ bfc,
               float* __restrict__ out)
{
    __shared__ alignas(16) _Float16 xs[TSEQ * XSTR];   // 24 KB fp16 input for this elem
    __shared__ alignas(16) _Float16 Abuf[2][128];      // state [y1(64);h2(64)], double-buffered
    __shared__ alignas(16) float    h2f[H];            // final h2 for FC

    const int tid = threadIdx.x;
    const int w   = tid >> 6;          // wave id -> h-units [16w, 16w+16)
    const int col = tid & 15;          // n within tile = h-unit offset
    const int qd  = (tid >> 4) & 3;    // quad: 0 -> layer-1 G, 2 -> layer-2 G
    const int hu  = 16 * w + col;      // this lane's G-phase h-unit
    const int b   = blockIdx.x;

    // ---------------- prologue: stage x (fp32 -> fp16, stride 5 -> 6) ----------------
    {
        const float* xb = x + (size_t)b * TSEQ * DIN;
        for (int idx = tid; idx < TSEQ * DIN; idx += 256) {
            int t = idx / DIN;
            int d = idx - t * DIN;
            xs[t * XSTR + d] = (_Float16)xb[idx];
        }
        for (int t = tid; t < TSEQ; t += 256)
            xs[t * XSTR + DIN] = (_Float16)0.0f;
    }
    if (tid < 256) ((_Float16*)Abuf)[tid] = (_Float16)0.0f;  // both buffers (2*128)

    // ---------------- B-fragments: weights, resident in registers ----------------
    // B[k=qd*8+j][n=col], n-tile g = gate-g rows {g*64 + hu}.
    f16x8 B1[4][2];   // layer-1: Whh0, K=64
    f16x8 B2[4][4];   // layer-2: [Wih1 | Whh1], K=128
    #pragma unroll
    for (int g = 0; g < 4; ++g) {
        const int row = g * 64 + hu;
        #pragma unroll
        for (int kt = 0; kt < 2; ++kt) {
            const float* p = Whh0 + row * H + kt * 32 + qd * 8;
            f16x8 f;
            #pragma unroll
            for (int j = 0; j < 8; ++j) f[j] = (_Float16)p[j];
            B1[g][kt] = f;
        }
        #pragma unroll
        for (int kt = 0; kt < 2; ++kt) {
            const float* p = Wih1 + row * H + kt * 32 + qd * 8;
            f16x8 f;
            #pragma unroll
            for (int j = 0; j < 8; ++j) f[j] = (_Float16)p[j];
            B2[g][kt] = f;
        }
        #pragma unroll
        for (int kt = 0; kt < 2; ++kt) {
            const float* p = Whh1 + row * H + kt * 32 + qd * 8;
            f16x8 f;
            #pragma unroll
            for (int j = 0; j < 8; ++j) f[j] = (_Float16)p[j];
            B2[g][2 + kt] = f;
        }
    }

    // ---------------- G-phase constants (per lane: its hu's 4 gate rows) ----------------
    half2v w0x[4][3];
    float  bias0g[4], bias1g[4];
    #pragma unroll
    for (int g = 0; g < 4; ++g) {
        const int row = g * 64 + hu;
        const float* r = Wih0 + row * DIN;
        w0x[g][0] = half2v{(_Float16)r[0], (_Float16)r[1]};
        w0x[g][1] = half2v{(_Float16)r[2], (_Float16)r[3]};
        w0x[g][2] = half2v{(_Float16)r[4], (_Float16)0.0f};
        bias0g[g] = bih0[row] + bhh0[row];
        bias1g[g] = bih1[row] + bhh1[row];
    }

    float cst = 0.0f;      // c1 (quad 0) or c2 (quad 2) for hu
    float h2fin = 0.0f;
    const f32x4 zz = {0.0f, 0.0f, 0.0f, 0.0f};

    __syncthreads();

    // ============ main loop: iter i = layer-1(t=i) + layer-2(t=i-1), ONE barrier ============
    #pragma unroll 1
    for (int i = 0; i <= TSEQ; ++i) {
        // ---- M: A-frags from state buf[(i-1)&1], broadcast to all rows; 24 mfma ----
        const _Float16* src = Abuf[(i + 1) & 1];
        f16x8 af[4];
        #pragma unroll
        for (int kt = 0; kt < 4; ++kt)
            af[kt] = *(const f16x8*)&src[kt * 32 + qd * 8];

        f32x4 d1[4], d2[4];
        #pragma unroll
        for (int g = 0; g < 4; ++g) {
            d1[g] = __builtin_amdgcn_mfma_f32_16x16x32_f16(af[0], B1[g][0], zz, 0, 0, 0);
            d1[g] = __builtin_amdgcn_mfma_f32_16x16x32_f16(af[1], B1[g][1], d1[g], 0, 0, 0);
            d2[g] = __builtin_amdgcn_mfma_f32_16x16x32_f16(af[0], B2[g][0], zz, 0, 0, 0);
            d2[g] = __builtin_amdgcn_mfma_f32_16x16x32_f16(af[1], B2[g][1], d2[g], 0, 0, 0);
            d2[g] = __builtin_amdgcn_mfma_f32_16x16x32_f16(af[2], B2[g][2], d2[g], 0, 0, 0);
            d2[g] = __builtin_amdgcn_mfma_f32_16x16x32_f16(af[3], B2[g][3], d2[g], 0, 0, 0);
        }
        // All D rows identical (broadcast A) -> use reg 0 (.x) in any quad.

        _Float16* wbuf = Abuf[i & 1];
        if (qd == 0) {
            if (i < TSEQ) {   // layer-1 update for t = i
                const half2v* xv = (const half2v*)(xs + i * XSTR);
                half2v xa = xv[0], xb = xv[1], xc = xv[2];
                float p0 = FDOT2(xc, w0x[0][2], FDOT2(xb, w0x[0][1], FDOT2(xa, w0x[0][0], bias0g[0])));
                float p1 = FDOT2(xc, w0x[1][2], FDOT2(xb, w0x[1][1], FDOT2(xa, w0x[1][0], bias0g[1])));
                float p2 = FDOT2(xc, w0x[2][2], FDOT2(xb, w0x[2][1], FDOT2(xa, w0x[2][0], bias0g[2])));
                float p3 = FDOT2(xc, w0x[3][2], FDOT2(xb, w0x[3][1], FDOT2(xa, w0x[3][0], bias0g[3])));
                float iv = sigmoid_fast(p0 + d1[0].x);
                float fv = sigmoid_fast(p1 + d1[1].x);
                float gv = tanh_fast(p2 + d1[2].x);
                float ov = sigmoid_fast(p3 + d1[3].x);
                cst = fmaf(fv, cst, iv * gv);
                wbuf[hu] = (_Float16)(ov * tanh_fast(cst));
            }
        } else if (qd == 2) {
            if (i > 0) {      // layer-2 update for t = i-1
                float iv = sigmoid_fast(bias1g[0] + d2[0].x);
                float fv = sigmoid_fast(bias1g[1] + d2[1].x);
                float gv = tanh_fast(bias1g[2] + d2[2].x);
                float ov = sigmoid_fast(bias1g[3] + d2[3].x);
                cst = fmaf(fv, cst, iv * gv);
                h2fin = ov * tanh_fast(cst);
                wbuf[64 + hu] = (_Float16)h2fin;
            }
        }
        __syncthreads();   // buf[i&1] ready for iter i+1; fences WAR on buf[(i-1)&1]
    }

    // ---------------- epilogue: out = relu(h2(T-1) @ Wfc^T + bfc) ----------------
    if (qd == 2) h2f[hu] = h2fin;   // h2 lives in quad-2 lanes
    __syncthreads();
    if (tid < NOUT) {
        const int o = tid;
        const float4* wr = (const float4*)(Wfc + o * H);
        const float*  hv = h2f;
        float s0 = 0.0f, s1 = 0.0f, s2 = 0.0f, s3 = 0.0f;
        #pragma unroll
        for (int k = 0; k < H / 4; ++k) {
            float4 wv = wr[k];
            s0 = fmaf(wv.x, hv[4 * k + 0], s0);
            s1 = fmaf(wv.y, hv[4 * k + 1], s1);
            s2 = fmaf(wv.z, hv[4 * k + 2], s2);
            s3 = fmaf(wv.w, hv[4 * k + 3], s3);
        }
        float acc = bfc[o] + (s0 + s1) + (s2 + s3);
        out[(size_t)b * NOUT + o] = fmaxf(acc, 0.0f);
    }
}

extern "C" void kernel_launch(void* const* d_in, const int* in_sizes, int n_in,
                              void* d_out, int out_size, void* d_ws, size_t ws_size,
                              hipStream_t stream) {
    const float* x    = (const float*)d_in[0];
    const float* Wih0 = (const float*)d_in[1];
    const float* Whh0 = (const float*)d_in[2];
    const float* bih0 = (const float*)d_in[3];
    const float* bhh0 = (const float*)d_in[4];
    const float* Wih1 = (const float*)d_in[5];
    const float* Whh1 = (const float*)d_in[6];
    const float* bih1 = (const float*)d_in[7];
    const float* bhh1 = (const float*)d_in[8];
    const float* Wfc  = (const float*)d_in[9];
    const float* bfc  = (const float*)d_in[10];
    float* out = (float*)d_out;

    lstm_mfma<<<dim3(BATCH), dim3(256), 0, stream>>>(
        x, Wih0, Whh0, bih0, bhh0, Wih1, Whh1, bih1, bhh1, Wfc, bfc, out);
}

// Round 7
// 2021.307 us; speedup vs baseline: 1.4329x; 1.4329x over previous
//
#include <hip/hip_runtime.h>
#include <math.h>

#define BATCH 1024
#define TSEQ  2048
#define DIN   5
#define H     64
#define BT    16     // batch elems per block (fills MFMA tile), grid = 64
#define SSTR  168    // state stride in halves: 336 B, 16B-aligned, 2-way-bank (free)
#define NOUT  128

typedef _Float16 f16x8 __attribute__((ext_vector_type(8)));
typedef float    f32x4 __attribute__((ext_vector_type(4)));

#if __has_builtin(__builtin_amdgcn_rcpf)
__device__ __forceinline__ float rcp_fast(float x) { return __builtin_amdgcn_rcpf(x); }
#else
__device__ __forceinline__ float rcp_fast(float x) { return 1.0f / x; }
#endif

// exp2-based activations; weights/biases pre-scaled by log2e (sigmoid gates)
// or 2*log2e (tanh gate) so NO per-use multiply is needed.
__device__ __forceinline__ float sigm2(float q) {   // q = log2e * p
    return rcp_fast(1.0f + __builtin_amdgcn_exp2f(-q));
}
__device__ __forceinline__ float tanh2(float q) {   // q = 2*log2e * p
    return fmaf(-2.0f, rcp_fast(__builtin_amdgcn_exp2f(q) + 1.0f), 1.0f);
}
#define LOG2E 1.44269504088896f

// BT=16 transposed-MFMA LSTM. A = state (m = elem, 16 rows all used),
// B = weight columns (n-tile g = gate-g rows for this wave's 16 h-units).
// Layer-1 K=96 ([y1(64) | x(5 pad 32)]) folds the input projection into MFMA.
// Bias enters via the MFMA C operand (pre-scaled). After 28 MFMAs, lane
// (wave w, quad q, col) holds all 4 gate raws of h-unit hu=16w+col for elems
// {4q+r} (regs r), BOTH layers -> 8 fully-packed in-register G tasks/lane.
// State double-buffered, ONE barrier/timestep. Grid 64 -> 1 block/CU.
__global__ __launch_bounds__(256) __attribute__((amdgpu_waves_per_eu(1)))
void lstm_mfma(const float* __restrict__ x,
               const float* __restrict__ Wih0, const float* __restrict__ Whh0,
               const float* __restrict__ bih0, const float* __restrict__ bhh0,
               const float* __restrict__ Wih1, const float* __restrict__ Whh1,
               const float* __restrict__ bih1, const float* __restrict__ bhh1,
               const float* __restrict__ Wfc,  const float* __restrict__ bfc,
               float* __restrict__ out)
{
    // state S[buf][elem][0:64 y1 | 64:128 h2 | 128:133 x, pad->SSTR]
    __shared__ alignas(16) _Float16 S[2][BT * SSTR];     // 10.5 KB
    __shared__ alignas(16) float    h2f[BT][H];          // 4 KB (FC epilogue)

    const int tid = threadIdx.x;
    const int w   = tid >> 6;         // wave -> h-units [16w, 16w+16)
    const int col = tid & 15;         // n within tile; also A-elem for ds_read
    const int q   = (tid >> 4) & 3;   // quad -> G elems {4q..4q+3}
    const int hu  = 16 * w + col;
    const int b0  = blockIdx.x * BT;

    // ---- zero both state buffers (x-pad region must stay 0 forever) ----
    for (int j = tid; j < 2 * BT * SSTR; j += 256)
        ((_Float16*)S)[j] = (_Float16)0.0f;

    const float sgl[4] = {LOG2E, LOG2E, 2.0f * LOG2E, LOG2E};  // i,f,g,o scales

    // ---- B-fragments (weights, registers, pre-scaled) ----
    // B[k = q*8+j][n = col]; n-tile g = gate rows g*64 + hu.
    f16x8 B1[4][3];   // layer-1: [Whh0 (K 0..63) | Wih0 (K 64..95, cols>=5 zero)]
    f16x8 B2[4][4];   // layer-2: [Wih1 (K 0..63) | Whh1 (K 64..127)]
    f32x4 bC1[4], bC2[4];
    #pragma unroll
    for (int g = 0; g < 4; ++g) {
        const int   row = g * 64 + hu;
        const float sg  = sgl[g];
        #pragma unroll
        for (int kt = 0; kt < 2; ++kt) {
            f16x8 f;
            #pragma unroll
            for (int j = 0; j < 8; ++j)
                f[j] = (_Float16)(Whh0[row * H + kt * 32 + q * 8 + j] * sg);
            B1[g][kt] = f;
        }
        {   // k-tile 2: Wih0 (K-local 0..31, only 0..4 nonzero)
            f16x8 f;
            #pragma unroll
            for (int j = 0; j < 8; ++j) {
                int kk = q * 8 + j;
                f[j] = (_Float16)(kk < DIN ? Wih0[row * DIN + kk] * sg : 0.0f);
            }
            B1[g][2] = f;
        }
        #pragma unroll
        for (int kt = 0; kt < 2; ++kt) {
            f16x8 f;
            #pragma unroll
            for (int j = 0; j < 8; ++j)
                f[j] = (_Float16)(Wih1[row * H + kt * 32 + q * 8 + j] * sg);
            B2[g][kt] = f;
        }
        #pragma unroll
        for (int kt = 0; kt < 2; ++kt) {
            f16x8 f;
            #pragma unroll
            for (int j = 0; j < 8; ++j)
                f[j] = (_Float16)(Whh1[row * H + kt * 32 + q * 8 + j] * sg);
            B2[g][2 + kt] = f;
        }
        const float b1 = (bih0[row] + bhh0[row]) * sg;
        const float b2 = (bih1[row] + bhh1[row]) * sg;
        bC1[g] = f32x4{b1, b1, b1, b1};
        bC2[g] = f32x4{b2, b2, b2, b2};
    }

    // ---- x staging lanes: thread (xe, xd) owns x[b0+xe, t, xd] ----
    const int  xe   = tid >> 3;
    const int  xd   = tid & 7;
    const bool xact = (tid < 128) && (xd < DIN);
    __syncthreads();   // S zero-fill done before writing x(t=0)
    if (xact)
        S[1][xe * SSTR + 128 + xd] =
            (_Float16)x[(size_t)(b0 + xe) * TSEQ * DIN + xd];   // t = 0

    float c1[4] = {0.f, 0.f, 0.f, 0.f};
    float c2[4] = {0.f, 0.f, 0.f, 0.f};
    float h2v[4] = {0.f, 0.f, 0.f, 0.f};

    __syncthreads();

    // ============ main loop: iter i = layer-1(t=i) + layer-2(t=i-1) ============
    #pragma unroll 1
    for (int i = 0; i <= TSEQ; ++i) {
        // prefetch next-timestep x (used at loop end)
        float xn = 0.0f;
        const bool xld = xact && (i + 1 < TSEQ);
        if (xld)
            xn = x[(size_t)(b0 + xe) * TSEQ * DIN + (i + 1) * DIN + xd];

        // ---- A-fragments: this lane supplies elem (col)'s state ----
        const _Float16* src = S[(i + 1) & 1];
        const int abase = col * SSTR + q * 8;
        f16x8 ay0 = *(const f16x8*)&src[abase];          // y1 k 0..31
        f16x8 ay1 = *(const f16x8*)&src[abase + 32];     // y1 k 32..63
        f16x8 ah0 = *(const f16x8*)&src[abase + 64];     // h2 k 0..31
        f16x8 ah1 = *(const f16x8*)&src[abase + 96];     // h2 k 32..63
        f16x8 ax  = *(const f16x8*)&src[abase + 128];    // x  k 0..31 (pad 0)

        f32x4 d1[4], d2[4];
        #pragma unroll
        for (int g = 0; g < 4; ++g) {
            d1[g] = __builtin_amdgcn_mfma_f32_16x16x32_f16(ay0, B1[g][0], bC1[g], 0, 0, 0);
            d1[g] = __builtin_amdgcn_mfma_f32_16x16x32_f16(ay1, B1[g][1], d1[g], 0, 0, 0);
            d1[g] = __builtin_amdgcn_mfma_f32_16x16x32_f16(ax,  B1[g][2], d1[g], 0, 0, 0);
            d2[g] = __builtin_amdgcn_mfma_f32_16x16x32_f16(ay0, B2[g][0], bC2[g], 0, 0, 0);
            d2[g] = __builtin_amdgcn_mfma_f32_16x16x32_f16(ay1, B2[g][1], d2[g], 0, 0, 0);
            d2[g] = __builtin_amdgcn_mfma_f32_16x16x32_f16(ah0, B2[g][2], d2[g], 0, 0, 0);
            d2[g] = __builtin_amdgcn_mfma_f32_16x16x32_f16(ah1, B2[g][3], d2[g], 0, 0, 0);
        }

        // ---- G: 8 in-register tasks (4 elems x 2 layers), all lanes active ----
        _Float16* wb = S[i & 1];
        const int gbase = 4 * q * SSTR + hu;   // elem 4q, +r*SSTR for reg r
        if (i < TSEQ) {   // layer-1 for t = i
            #pragma unroll
            for (int r = 0; r < 4; ++r) {
                float iv = sigm2(d1[0][r]);
                float fv = sigm2(d1[1][r]);
                float gv = tanh2(d1[2][r]);
                float ov = sigm2(d1[3][r]);
                c1[r] = fmaf(fv, c1[r], iv * gv);
                wb[gbase + r * SSTR] = (_Float16)(ov * tanh2(2.0f * LOG2E * c1[r]));
            }
        }
        if (i > 0) {      // layer-2 for t = i-1
            #pragma unroll
            for (int r = 0; r < 4; ++r) {
                float iv = sigm2(d2[0][r]);
                float fv = sigm2(d2[1][r]);
                float gv = tanh2(d2[2][r]);
                float ov = sigm2(d2[3][r]);
                c2[r] = fmaf(fv, c2[r], iv * gv);
                h2v[r] = ov * tanh2(2.0f * LOG2E * c2[r]);
                wb[gbase + r * SSTR + 64] = (_Float16)h2v[r];
            }
        }
        if (xld)
            wb[xe * SSTR + 128 + xd] = (_Float16)xn;   // x(t=i+1) for next iter

        __syncthreads();
    }

    // ---------------- epilogue: out = relu(h2(T-1) @ Wfc^T + bfc) ----------------
    #pragma unroll
    for (int r = 0; r < 4; ++r)
        h2f[4 * q + r][hu] = h2v[r];
    __syncthreads();
    {
        const int o  = tid & (NOUT - 1);
        const int eb = (tid >> 7) * 8;     // 8 elems per thread
        const float4* wr = (const float4*)(Wfc + o * H);
        float4 wv[H / 4];
        #pragma unroll
        for (int k = 0; k < H / 4; ++k) wv[k] = wr[k];
        const float bo = bfc[o];
        #pragma unroll
        for (int ee = 0; ee < 8; ++ee) {
            const int e = eb + ee;
            const float* hv = h2f[e];
            float s0 = 0.f, s1 = 0.f, s2 = 0.f, s3 = 0.f;
            #pragma unroll
            for (int k = 0; k < H / 4; ++k) {
                float4 v = wv[k];
                s0 = fmaf(v.x, hv[4 * k + 0], s0);
                s1 = fmaf(v.y, hv[4 * k + 1], s1);
                s2 = fmaf(v.z, hv[4 * k + 2], s2);
                s3 = fmaf(v.w, hv[4 * k + 3], s3);
            }
            float acc = bo + (s0 + s1) + (s2 + s3);
            out[(size_t)(b0 + e) * NOUT + o] = fmaxf(acc, 0.0f);
        }
    }
}

extern "C" void kernel_launch(void* const* d_in, const int* in_sizes, int n_in,
                              void* d_out, int out_size, void* d_ws, size_t ws_size,
                              hipStream_t stream) {
    const float* x    = (const float*)d_in[0];
    const float* Wih0 = (const float*)d_in[1];
    const float* Whh0 = (const float*)d_in[2];
    const float* bih0 = (const float*)d_in[3];
    const float* bhh0 = (const float*)d_in[4];
    const float* Wih1 = (const float*)d_in[5];
    const float* Whh1 = (const float*)d_in[6];
    const float* bih1 = (const float*)d_in[7];
    const float* bhh1 = (const float*)d_in[8];
    const float* Wfc  = (const float*)d_in[9];
    const float* bfc  = (const float*)d_in[10];
    float* out = (float*)d_out;

    lstm_mfma<<<dim3(BATCH / BT), dim3(256), 0, stream>>>(
        x, Wih0, Whh0, bih0, bhh0, Wih1, Whh1, bih1, bhh1, Wfc, bfc, out);
}

// Round 8
// 1049.662 us; speedup vs baseline: 2.7592x; 1.9257x over previous
//
#include <hip/hip_runtime.h>
#include <math.h>

#define BATCH 1024
#define TSEQ  2048
#define DIN   5
#define H     64
#define BT    4      // elems per block; grid 256 = every CU
#define SSTR  160    // halves/elem: [h1 64 | h2 64 | x 32]; word-stride 80 = 16 mod 32 -> 2-way banks (free)
#define NOUT  128

typedef _Float16 f16x8 __attribute__((ext_vector_type(8)));
typedef float    f32x4 __attribute__((ext_vector_type(4)));

#if __has_builtin(__builtin_amdgcn_rcpf)
__device__ __forceinline__ float rcp_fast(float x) { return __builtin_amdgcn_rcpf(x); }
#else
__device__ __forceinline__ float rcp_fast(float x) { return 1.0f / x; }
#endif

#define LOG2E 1.44269504088896f

// exp2-based activations; weights/biases pre-scaled by log2e (sigmoid) or
// 2*log2e (tanh gate) so no per-use multiply.
__device__ __forceinline__ float sigm2(float s) {   // s = log2e * p
    return rcp_fast(1.0f + __builtin_amdgcn_exp2f(-s));
}
__device__ __forceinline__ float tanh2(float s) {   // s = 2*log2e * p
    return fmaf(-2.0f, rcp_fast(__builtin_amdgcn_exp2f(s) + 1.0f), 1.0f);
}

// 512-thread block = 8 waves, BT=4 elems, grid 256 (all CUs, 2 waves/SIMD).
// Transposed MFMA: A = state with elem = m>>2 (so D rows 4q+r are ALL elem q:
// every lane reads D reg 0 -- zero dynamic selects). B = weight columns for
// this wave's 16 h-units x 4 gates. Waves 0-3: layer-1 (K=96, x folded in);
// waves 4-7: layer-2 (K=128). All 4 gates of (hu, elem) land in-lane -> G is
// one fully in-register task/lane. Bias via MFMA C; exp2 pre-scaling.
// State double-buffered (2.5 KB), ONE barrier per timestep.
__global__ __launch_bounds__(512)
void lstm_mfma(const float* __restrict__ x,
               const float* __restrict__ Wih0, const float* __restrict__ Whh0,
               const float* __restrict__ bih0, const float* __restrict__ bhh0,
               const float* __restrict__ Wih1, const float* __restrict__ Whh1,
               const float* __restrict__ bih1, const float* __restrict__ bhh1,
               const float* __restrict__ Wfc,  const float* __restrict__ bfc,
               float* __restrict__ out)
{
    __shared__ alignas(16) _Float16 S[2][BT * SSTR];   // 2.5 KB state, double-buffered
    __shared__ alignas(16) float    h2f[BT][H];        // 1 KB final h2 for FC

    const int tid  = threadIdx.x;
    const int w    = tid >> 6;         // 0..7
    const int lane = tid & 63;
    const int col  = lane & 15;        // n within tile = h-unit offset; also A-row m
    const int q    = lane >> 4;        // quad -> G elem
    const int ww   = w & 3;            // h-unit tile: hu in [16ww, 16ww+16)
    const int lay  = w >> 2;           // 0 = layer-1, 1 = layer-2
    const int hu   = 16 * ww + col;
    const int b0   = blockIdx.x * BT;

    // ---- zero both state buffers (x pad must stay 0) ----
    for (int j = tid; j < 2 * BT * SSTR; j += 512)
        ((_Float16*)S)[j] = (_Float16)0.0f;

    const float sgl[4] = {LOG2E, LOG2E, 2.0f * LOG2E, LOG2E};  // i,f,g,o

    // ---- B-fragments (this wave's layer only), pre-scaled, registers ----
    // B[k=q*8+j][n=col]; n-tile g = gate rows g*64 + hu.
    f16x8 Bf[4][4];
    f32x4 bC[4];
    #pragma unroll
    for (int g = 0; g < 4; ++g) {
        const int   row = g * 64 + hu;
        const float sg  = sgl[g];
        const float* Wa = lay ? (Wih1 + row * H) : (Whh0 + row * H);
        f16x8 f0, f1, f2, f3;
        #pragma unroll
        for (int j = 0; j < 8; ++j) {
            f0[j] = (_Float16)(Wa[q * 8 + j] * sg);
            f1[j] = (_Float16)(Wa[32 + q * 8 + j] * sg);
        }
        if (lay) {
            const float* Wb = Whh1 + row * H;
            #pragma unroll
            for (int j = 0; j < 8; ++j) {
                f2[j] = (_Float16)(Wb[q * 8 + j] * sg);
                f3[j] = (_Float16)(Wb[32 + q * 8 + j] * sg);
            }
        } else {
            #pragma unroll
            for (int j = 0; j < 8; ++j) {
                const int kk = q * 8 + j;
                f2[j] = (_Float16)(kk < DIN ? Wih0[row * DIN + kk] * sg : 0.0f);
                f3[j] = (_Float16)0.0f;
            }
        }
        Bf[g][0] = f0; Bf[g][1] = f1; Bf[g][2] = f2; Bf[g][3] = f3;
        const float bb = (lay ? (bih1[row] + bhh1[row])
                              : (bih0[row] + bhh0[row])) * sg;
        bC[g] = f32x4{bb, bb, bb, bb};
    }

    // ---- x staging lanes: layer-1 wave ww stages elem ww, lanes 0..4 = dims ----
    const bool xlane = (lay == 0) && (lane < DIN);
    __syncthreads();                       // zero-fill done
    if (xlane)
        S[1][ww * SSTR + 128 + lane] =
            (_Float16)x[(size_t)(b0 + ww) * TSEQ * DIN + lane];   // x(t=0)

    // A-frag base (this lane supplies A row m=col -> elem col>>2) and offsets
    const int abase = (col >> 2) * SSTR + q * 8;
    const int aoff2 = lay ? 64 : 128;      // k-tile 2: h2(0..31) vs x
    float cst = 0.0f, h2fin = 0.0f;

    __syncthreads();

    // ============ main loop: iter i = layer-1(t=i) & layer-2(t=i-1) ============
    #pragma unroll 1
    for (int i = 0; i <= TSEQ; ++i) {
        const _Float16* rb = S[(i + 1) & 1];
        _Float16*       wb = S[i & 1];

        // prefetch next x early (hide global latency under MFMA)
        float xn = 0.0f;
        const bool xld = xlane && (i + 1 < TSEQ);
        if (xld)
            xn = x[(size_t)(b0 + ww) * TSEQ * DIN + (i + 1) * DIN + lane];

        // A-fragments
        f16x8 a0 = *(const f16x8*)&rb[abase];          // h1 k 0..31
        f16x8 a1 = *(const f16x8*)&rb[abase + 32];     // h1 k 32..63
        f16x8 a2 = *(const f16x8*)&rb[abase + aoff2];  // h2 k0..31 | x
        f16x8 a3 = *(const f16x8*)&rb[abase + 96];     // h2 k 32..63 (lay1 only)

        f32x4 d[4];
        #pragma unroll
        for (int g = 0; g < 4; ++g) {
            d[g] = __builtin_amdgcn_mfma_f32_16x16x32_f16(a0, Bf[g][0], bC[g], 0, 0, 0);
            d[g] = __builtin_amdgcn_mfma_f32_16x16x32_f16(a1, Bf[g][1], d[g], 0, 0, 0);
            d[g] = __builtin_amdgcn_mfma_f32_16x16x32_f16(a2, Bf[g][2], d[g], 0, 0, 0);
        }
        if (lay) {
            #pragma unroll
            for (int g = 0; g < 4; ++g)
                d[g] = __builtin_amdgcn_mfma_f32_16x16x32_f16(a3, Bf[g][3], d[g], 0, 0, 0);
        }

        // ---- G: one in-register task (hu, elem=q, this layer); reg 0 only ----
        const bool act = lay ? (i > 0) : (i < TSEQ);
        if (act) {
            float iv = sigm2(d[0][0]);
            float fv = sigm2(d[1][0]);
            float gv = tanh2(d[2][0]);
            float ov = sigm2(d[3][0]);
            cst = fmaf(fv, cst, iv * gv);
            float h = ov * tanh2(2.0f * LOG2E * cst);
            wb[q * SSTR + lay * 64 + hu] = (_Float16)h;
            h2fin = h;                     // meaningful on lay==1 waves
        }
        if (xld)
            wb[ww * SSTR + 128 + lane] = (_Float16)xn;   // x(t=i+1)

        __syncthreads();
    }

    // ---------------- epilogue: out = relu(h2(T-1) @ Wfc^T + bfc) ----------------
    if (lay) h2f[q][hu] = h2fin;
    __syncthreads();
    {
        const int e = tid >> 7;            // 0..3
        const int o = tid & (NOUT - 1);    // 0..127
        const float4* wr = (const float4*)(Wfc + o * H);
        const float*  hv = h2f[e];
        float s0 = 0.f, s1 = 0.f, s2 = 0.f, s3 = 0.f;
        #pragma unroll
        for (int k = 0; k < H / 4; ++k) {
            float4 wv = wr[k];
            s0 = fmaf(wv.x, hv[4 * k + 0], s0);
            s1 = fmaf(wv.y, hv[4 * k + 1], s1);
            s2 = fmaf(wv.z, hv[4 * k + 2], s2);
            s3 = fmaf(wv.w, hv[4 * k + 3], s3);
        }
        float acc = bfc[o] + (s0 + s1) + (s2 + s3);
        out[(size_t)(b0 + e) * NOUT + o] = fmaxf(acc, 0.0f);
    }
}

extern "C" void kernel_launch(void* const* d_in, const int* in_sizes, int n_in,
                              void* d_out, int out_size, void* d_ws, size_t ws_size,
                              hipStream_t stream) {
    const float* x    = (const float*)d_in[0];
    const float* Wih0 = (const float*)d_in[1];
    const float* Whh0 = (const float*)d_in[2];
    const float* bih0 = (const float*)d_in[3];
    const float* bhh0 = (const float*)d_in[4];
    const float* Wih1 = (const float*)d_in[5];
    const float* Whh1 = (const float*)d_in[6];
    const float* bih1 = (const float*)d_in[7];
    const float* bhh1 = (const float*)d_in[8];
    const float* Wfc  = (const float*)d_in[9];
    const float* bfc  = (const float*)d_in[10];
    float* out = (float*)d_out;

    lstm_mfma<<<dim3(BATCH / BT), dim3(512), 0, stream>>>(
        x, Wih0, Whh0, bih0, bhh0, Wih1, Whh1, bih1, bhh1, Wfc, bfc, out);
}